// Round 1
// baseline (641.732 us; speedup 1.0000x reference)
//
#include <hip/hip_runtime.h>
#include <stdint.h>

typedef unsigned short u16;
typedef uint32_t u32;
typedef __attribute__((ext_vector_type(8))) short short8;
typedef __attribute__((ext_vector_type(4))) float f32x4;
typedef __attribute__((ext_vector_type(4))) u32 u32x4;
typedef __attribute__((ext_vector_type(4))) unsigned short u16x4;

#define BS_ 4096   // B*S rows
#define S_ 2048
#define HID_ 2048

__device__ __forceinline__ float bf2f(u16 u) { union { u32 i; float f; } v; v.i = ((u32)u) << 16; return v.f; }
__device__ __forceinline__ u16 f2bf(float f) {
  union { float f; u32 i; } v; v.f = f;
  u32 r = v.i + 0x7fffu + ((v.i >> 16) & 1u);
  return (u16)(r >> 16);
}

__device__ __forceinline__ void gload16(const void* gsrc, void* ldst) {
  __builtin_amdgcn_global_load_lds(
      (const __attribute__((address_space(1))) void*)gsrc,
      (__attribute__((address_space(3))) void*)ldst, 16, 0, 0);
}

// ---------------- elementwise convert fp32 -> bf16 ----------------
__global__ __launch_bounds__(256) void conv_f2b(const float* __restrict__ in, u16* __restrict__ out, int n4) {
  int i = blockIdx.x * 256 + threadIdx.x;
  if (i < n4) {
    float4 v = ((const float4*)in)[i];
    u16x4 o;
    o.x = f2bf(v.x); o.y = f2bf(v.y); o.z = f2bf(v.z); o.w = f2bf(v.w);
    ((u16x4*)out)[i] = o;
  }
}

// ---------------- transpose + convert: W[K][N] fp32 -> WT[N][K] bf16 ----------------
__global__ __launch_bounds__(256) void transpose_conv(const float* __restrict__ W, u16* __restrict__ WT,
                                                      int K, int N) {
  __shared__ float tile[64][65];
  const int t = threadIdx.x;
  const int kb = blockIdx.y * 64, nb = blockIdx.x * 64;
#pragma unroll
  for (int c = 0; c < 4; ++c) {
    int idx = c * 256 + t;          // 0..1023, 4 floats each
    int row = idx >> 4;             // 64 rows
    int col4 = (idx & 15) * 4;
    float4 v = *(const float4*)&W[(size_t)(kb + row) * N + nb + col4];
    tile[row][col4 + 0] = v.x; tile[row][col4 + 1] = v.y;
    tile[row][col4 + 2] = v.z; tile[row][col4 + 3] = v.w;
  }
  __syncthreads();
#pragma unroll
  for (int c = 0; c < 4; ++c) {
    int idx = c * 256 + t;
    int n = idx >> 4;
    int k4 = (idx & 15) * 4;
    u16x4 o;
    o.x = f2bf(tile[k4 + 0][n]); o.y = f2bf(tile[k4 + 1][n]);
    o.z = f2bf(tile[k4 + 2][n]); o.w = f2bf(tile[k4 + 3][n]);
    *(u16x4*)&WT[(size_t)(nb + n) * K + kb + k4] = o;
  }
}

// ---------------- RoPE table: [2048][64] cos/sin ----------------
__global__ __launch_bounds__(256) void rope_table(float* __restrict__ ct, float* __restrict__ st) {
  int idx = blockIdx.x * 256 + threadIdx.x;   // 2048*64
  int pos = idx >> 6, i = idx & 63;
  float inv = powf(10000.f, -(float)i / 64.f);
  float a = (float)pos * inv;
  ct[idx] = cosf(a);
  st[idx] = sinf(a);
}

// ---------------- RoPE apply in-place on bf16 [4096][2048] (u32 = pair) ----------------
__global__ __launch_bounds__(256) void rope_apply(u32* __restrict__ buf, const float* __restrict__ ct,
                                                  const float* __restrict__ st) {
  int idx = blockIdx.x * 256 + threadIdx.x;   // 4096*1024 pairs
  int s = (idx >> 10) & 2047;
  int i = idx & 63;
  u32 v = buf[idx];
  float x1 = bf2f((u16)(v & 0xffff)), x2 = bf2f((u16)(v >> 16));
  float c = ct[s * 64 + i], sn = st[s * 64 + i];
  float o1 = x1 * c - x2 * sn;
  float o2 = x1 * sn + x2 * c;
  buf[idx] = (u32)f2bf(o1) | ((u32)f2bf(o2) << 16);
}

// ---------------- GEMM: C[M][N] = A[M][K](bf16) * BT[N][K]^T(bf16) + bias ----------------
// 128x128 tile, BK=64, 256 threads = 4 waves (2x2), each wave 64x64.
template <int OUTF32>
__global__ __launch_bounds__(256) void gemm_bt(const u16* __restrict__ A, const u16* __restrict__ BT,
                                               const float* __restrict__ bias, void* __restrict__ Cout,
                                               int M, int N, int K) {
  __shared__ u16 As[128 * 64];
  __shared__ u16 Bs[128 * 64];
  const int t = threadIdx.x;
  const int lane = t & 63, wave = t >> 6;
  const int wm = wave >> 1, wn = wave & 1;
  const int tm = blockIdx.y, tn = blockIdx.x;
  const int r16 = lane & 15, q4 = lane >> 4;

  f32x4 acc[4][4];
#pragma unroll
  for (int m = 0; m < 4; ++m)
#pragma unroll
    for (int n = 0; n < 4; ++n) acc[m][n] = (f32x4){0.f, 0.f, 0.f, 0.f};

  for (int kt = 0; kt < K; kt += 64) {
#pragma unroll
    for (int c = 0; c < 4; ++c) {
      int idx = c * 256 + t;
      int row = idx >> 3, ch = idx & 7;
      gload16(&A[(size_t)(tm * 128 + row) * K + kt + ch * 8], (char*)As + idx * 16);
      gload16(&BT[(size_t)(tn * 128 + row) * K + kt + ch * 8], (char*)Bs + idx * 16);
    }
    __syncthreads();
#pragma unroll
    for (int kk = 0; kk < 64; kk += 32) {
      short8 af[4], bfv[4];
#pragma unroll
      for (int m = 0; m < 4; ++m)
        af[m] = *(const short8*)&As[(wm * 64 + m * 16 + r16) * 64 + kk + q4 * 8];
#pragma unroll
      for (int n = 0; n < 4; ++n)
        bfv[n] = *(const short8*)&Bs[(wn * 64 + n * 16 + r16) * 64 + kk + q4 * 8];
#pragma unroll
      for (int m = 0; m < 4; ++m)
#pragma unroll
        for (int n = 0; n < 4; ++n)
          acc[m][n] = __builtin_amdgcn_mfma_f32_16x16x32_bf16(af[m], bfv[n], acc[m][n], 0, 0, 0);
    }
    __syncthreads();
  }
  // epilogue: bias + store
#pragma unroll
  for (int n = 0; n < 4; ++n) {
    int gc = tn * 128 + wn * 64 + n * 16 + r16;
    float bv = bias[gc];
#pragma unroll
    for (int m = 0; m < 4; ++m) {
      int gr0 = tm * 128 + wm * 64 + m * 16 + q4 * 4;
#pragma unroll
      for (int j = 0; j < 4; ++j) {
        float v = acc[m][n][j] + bv;
        if (OUTF32)
          ((float*)Cout)[(size_t)(gr0 + j) * N + gc] = v;
        else
          ((u16*)Cout)[(size_t)(gr0 + j) * N + gc] = f2bf(v);
      }
    }
  }
}

// ---------------- causal flash attention ----------------
// grid (16, 32): x -> qtile (reversed), y -> b*16+h. 256 thr = 4 waves x 32 q-rows.
__global__ __launch_bounds__(256) void attn_kernel(const u16* __restrict__ Q, const u16* __restrict__ K,
                                                   const u16* __restrict__ V, u16* __restrict__ O) {
  __shared__ u16 Kl[64 * 128];   // [kv][d]   swizzled
  __shared__ u16 Vt[128 * 64];   // [d][kv]   swizzled
  __shared__ u16 Pl[4][32 * 64]; // per-wave P, swizzled
  const int t = threadIdx.x;
  const int lane = t & 63, w = t >> 6;
  const int r16 = lane & 15, q4 = lane >> 4;
  const int qt = 15 - (int)blockIdx.x;
  const int bh = blockIdx.y;
  const int b = bh >> 4, h = bh & 15;
  const size_t headoff = (size_t)b * S_ * HID_ + (size_t)h * 128;
  const u16* Qb = Q + headoff;
  const u16* Kb = K + headoff;
  const u16* Vb = V + headoff;
  u16* Ob = O + headoff;
  const int qrow0 = qt * 128 + w * 32;

  short8 qf[2][4];
#pragma unroll
  for (int m = 0; m < 2; ++m)
#pragma unroll
    for (int dk = 0; dk < 4; ++dk)
      qf[m][dk] = *(const short8*)&Qb[(size_t)(qrow0 + m * 16 + r16) * HID_ + dk * 32 + q4 * 8];

  f32x4 ao[2][8];
  float mr[2][4], lr[2][4];
#pragma unroll
  for (int m = 0; m < 2; ++m) {
#pragma unroll
    for (int dn = 0; dn < 8; ++dn) ao[m][dn] = (f32x4){0.f, 0.f, 0.f, 0.f};
#pragma unroll
    for (int j = 0; j < 4; ++j) { mr[m][j] = -1e30f; lr[m][j] = 0.f; }
  }

  const int ntiles = 2 * qt + 2;
  for (int tile = 0; tile < ntiles; ++tile) {
    const int kv0 = tile * 64;
    __syncthreads();
    // stage K [64][128] with XOR swizzle
#pragma unroll
    for (int c = 0; c < 4; ++c) {
      int idx = c * 256 + t;
      int row = idx >> 4, ch = idx & 15;
      u32x4 d = *(const u32x4*)&Kb[(size_t)(kv0 + row) * HID_ + ch * 8];
      int ba = (row * 256 + ch * 16) ^ ((row & 7) << 4);
      *(u32x4*)((char*)Kl + ba) = d;
    }
    // stage V transposed [d][kv] with XOR swizzle
#pragma unroll
    for (int c = 0; c < 2; ++c) {
      int idx = c * 256 + t;          // 0..511
      int kv = (idx & 31) * 2;
      int d0 = (idx >> 5) * 8;
      short8 v0 = *(const short8*)&Vb[(size_t)(kv0 + kv) * HID_ + d0];
      short8 v1 = *(const short8*)&Vb[(size_t)(kv0 + kv + 1) * HID_ + d0];
#pragma unroll
      for (int j = 0; j < 8; ++j) {
        u32 pk = (u32)(u16)v0[j] | ((u32)(u16)v1[j] << 16);
        int d = d0 + j;
        int ba = (d * 128 + kv * 2) ^ ((d & 7) << 4);
        *(u32*)((char*)Vt + ba) = pk;
      }
    }
    __syncthreads();
    if (kv0 > qrow0 + 31) continue;   // fully masked for this wave

    // ---- QK^T ----
    f32x4 sc[2][4];
#pragma unroll
    for (int m = 0; m < 2; ++m)
#pragma unroll
      for (int n = 0; n < 4; ++n) sc[m][n] = (f32x4){0.f, 0.f, 0.f, 0.f};
#pragma unroll
    for (int dk = 0; dk < 4; ++dk) {
      short8 kf[4];
#pragma unroll
      for (int n = 0; n < 4; ++n) {
        int kr = n * 16 + r16;
        int ba = (kr * 256 + dk * 64 + q4 * 16) ^ ((kr & 7) << 4);
        kf[n] = *(const short8*)((char*)Kl + ba);
      }
#pragma unroll
      for (int m = 0; m < 2; ++m)
#pragma unroll
        for (int n = 0; n < 4; ++n)
          sc[m][n] = __builtin_amdgcn_mfma_f32_16x16x32_bf16(qf[m][dk], kf[n], sc[m][n], 0, 0, 0);
    }
    // ---- scale + causal mask ----
    const float SCALE = 0.08838834764831845f;
    const bool need_mask = (kv0 + 63 > qrow0);
#pragma unroll
    for (int m = 0; m < 2; ++m)
#pragma unroll
      for (int n = 0; n < 4; ++n)
#pragma unroll
        for (int j = 0; j < 4; ++j) {
          float sv = sc[m][n][j] * SCALE;
          if (need_mask) {
            int row = qrow0 + m * 16 + q4 * 4 + j;
            int col = kv0 + n * 16 + r16;
            if (col > row) sv = -1e30f;
          }
          sc[m][n][j] = sv;
        }
    // ---- online softmax (row = 16 lanes via shfl_xor) ----
#pragma unroll
    for (int m = 0; m < 2; ++m)
#pragma unroll
      for (int j = 0; j < 4; ++j) {
        float tmax = fmaxf(fmaxf(sc[m][0][j], sc[m][1][j]), fmaxf(sc[m][2][j], sc[m][3][j]));
        tmax = fmaxf(tmax, __shfl_xor(tmax, 1));
        tmax = fmaxf(tmax, __shfl_xor(tmax, 2));
        tmax = fmaxf(tmax, __shfl_xor(tmax, 4));
        tmax = fmaxf(tmax, __shfl_xor(tmax, 8));
        float mnew = fmaxf(mr[m][j], tmax);
        float fsc = __expf(mr[m][j] - mnew);
        float ps = 0.f;
#pragma unroll
        for (int n = 0; n < 4; ++n) {
          float p = __expf(sc[m][n][j] - mnew);
          sc[m][n][j] = p;
          ps += p;
        }
        ps += __shfl_xor(ps, 1);
        ps += __shfl_xor(ps, 2);
        ps += __shfl_xor(ps, 4);
        ps += __shfl_xor(ps, 8);
        lr[m][j] = lr[m][j] * fsc + ps;
        mr[m][j] = mnew;
#pragma unroll
        for (int dn = 0; dn < 8; ++dn) ao[m][dn][j] *= fsc;
      }
    // ---- P -> LDS (bf16, swizzled) ----
    u16* Pw = &Pl[w][0];
#pragma unroll
    for (int m = 0; m < 2; ++m)
#pragma unroll
      for (int n = 0; n < 4; ++n)
#pragma unroll
        for (int j = 0; j < 4; ++j) {
          int row = m * 16 + q4 * 4 + j;
          int col = n * 16 + r16;
          int ba = (row * 128 + col * 2) ^ ((row & 7) << 4);
          *(u16*)((char*)Pw + ba) = f2bf(sc[m][n][j]);
        }
    // ---- PV ----
#pragma unroll
    for (int kk = 0; kk < 2; ++kk) {
      short8 pa[2];
#pragma unroll
      for (int m = 0; m < 2; ++m) {
        int row = m * 16 + r16;
        int ba = (row * 128 + kk * 64 + q4 * 16) ^ ((row & 7) << 4);
        pa[m] = *(const short8*)((char*)Pw + ba);
      }
#pragma unroll
      for (int dn = 0; dn < 8; ++dn) {
        int dr = dn * 16 + r16;
        int ba = (dr * 128 + kk * 64 + q4 * 16) ^ ((dr & 7) << 4);
        short8 vf = *(const short8*)((char*)Vt + ba);
#pragma unroll
        for (int m = 0; m < 2; ++m)
          ao[m][dn] = __builtin_amdgcn_mfma_f32_16x16x32_bf16(pa[m], vf, ao[m][dn], 0, 0, 0);
      }
    }
  }
  // ---- epilogue ----
#pragma unroll
  for (int m = 0; m < 2; ++m)
#pragma unroll
    for (int j = 0; j < 4; ++j) {
      float inv = 1.f / lr[m][j];
      int row = qrow0 + m * 16 + q4 * 4 + j;
#pragma unroll
      for (int dn = 0; dn < 8; ++dn)
        Ob[(size_t)row * HID_ + dn * 16 + r16] = f2bf(ao[m][dn][j] * inv);
    }
}

// ---------------- host launch ----------------
extern "C" void kernel_launch(void* const* d_in, const int* in_sizes, int n_in,
                              void* d_out, int out_size, void* d_ws, size_t ws_size,
                              hipStream_t stream) {
  (void)in_sizes; (void)n_in; (void)out_size; (void)ws_size;
  const float* x     = (const float*)d_in[0];
  // d_in[1] attention_mask (causal tril) -- hard-coded causal
  const float* W_dkv = (const float*)d_in[2];
  const float* b_dkv = (const float*)d_in[3];
  const float* W_uk  = (const float*)d_in[4];
  const float* b_uk  = (const float*)d_in[5];
  const float* W_uv  = (const float*)d_in[6];
  const float* b_uv  = (const float*)d_in[7];
  const float* W_dq  = (const float*)d_in[8];
  const float* b_dq  = (const float*)d_in[9];
  const float* W_uq  = (const float*)d_in[10];
  const float* b_uq  = (const float*)d_in[11];
  const float* W_o   = (const float*)d_in[12];
  const float* b_o   = (const float*)d_in[13];
  float* out = (float*)d_out;

  char* ws = (char*)d_ws;
  size_t off = 0;
  auto carve = [&](size_t bytes) { void* p = ws + off; off += (bytes + 255) & ~(size_t)255; return p; };
  u16* xb    = (u16*)carve((size_t)BS_ * 2048 * 2);
  u16* WdkvT = (u16*)carve((size_t)512 * 2048 * 2);
  u16* WukT  = (u16*)carve((size_t)2048 * 512 * 2);
  u16* WuvT  = (u16*)carve((size_t)2048 * 512 * 2);
  u16* WdqT  = (u16*)carve((size_t)1536 * 2048 * 2);
  u16* WuqT  = (u16*)carve((size_t)2048 * 1536 * 2);
  u16* WoT   = (u16*)carve((size_t)2048 * 2048 * 2);
  u16* kvb   = (u16*)carve((size_t)BS_ * 512 * 2);
  u16* q1b   = (u16*)carve((size_t)BS_ * 1536 * 2);
  u16* qb    = (u16*)carve((size_t)BS_ * 2048 * 2);
  u16* kb    = (u16*)carve((size_t)BS_ * 2048 * 2);
  u16* vb    = (u16*)carve((size_t)BS_ * 2048 * 2);
  u16* aob   = (u16*)carve((size_t)BS_ * 2048 * 2);
  float* ct  = (float*)carve((size_t)2048 * 64 * 4);
  float* st  = (float*)carve((size_t)2048 * 64 * 4);

  conv_f2b<<<dim3(BS_ * 2048 / 4 / 256), 256, 0, stream>>>(x, xb, BS_ * 2048 / 4);
  transpose_conv<<<dim3(512 / 64, 2048 / 64), 256, 0, stream>>>(W_dkv, WdkvT, 2048, 512);
  transpose_conv<<<dim3(2048 / 64, 512 / 64), 256, 0, stream>>>(W_uk, WukT, 512, 2048);
  transpose_conv<<<dim3(2048 / 64, 512 / 64), 256, 0, stream>>>(W_uv, WuvT, 512, 2048);
  transpose_conv<<<dim3(1536 / 64, 2048 / 64), 256, 0, stream>>>(W_dq, WdqT, 2048, 1536);
  transpose_conv<<<dim3(2048 / 64, 1536 / 64), 256, 0, stream>>>(W_uq, WuqT, 1536, 2048);
  transpose_conv<<<dim3(2048 / 64, 2048 / 64), 256, 0, stream>>>(W_o, WoT, 2048, 2048);
  rope_table<<<dim3(512), 256, 0, stream>>>(ct, st);

  gemm_bt<0><<<dim3(512 / 128, BS_ / 128), 256, 0, stream>>>(xb, WdkvT, b_dkv, kvb, BS_, 512, 2048);
  gemm_bt<0><<<dim3(1536 / 128, BS_ / 128), 256, 0, stream>>>(xb, WdqT, b_dq, q1b, BS_, 1536, 2048);
  gemm_bt<0><<<dim3(2048 / 128, BS_ / 128), 256, 0, stream>>>(kvb, WukT, b_uk, kb, BS_, 2048, 512);
  gemm_bt<0><<<dim3(2048 / 128, BS_ / 128), 256, 0, stream>>>(kvb, WuvT, b_uv, vb, BS_, 2048, 512);
  gemm_bt<0><<<dim3(2048 / 128, BS_ / 128), 256, 0, stream>>>(q1b, WuqT, b_uq, qb, BS_, 2048, 1536);

  rope_apply<<<dim3(BS_ * 1024 / 256), 256, 0, stream>>>((u32*)qb, ct, st);
  rope_apply<<<dim3(BS_ * 1024 / 256), 256, 0, stream>>>((u32*)kb, ct, st);

  attn_kernel<<<dim3(16, 32), 256, 0, stream>>>(qb, kb, vb, aob);

  gemm_bt<1><<<dim3(2048 / 128, BS_ / 128), 256, 0, stream>>>(aob, WoT, b_o, out, BS_, 2048, 2048);
}

// Round 2
// 469.231 us; speedup vs baseline: 1.3676x; 1.3676x over previous
//
#include <hip/hip_runtime.h>
#include <stdint.h>

typedef unsigned short u16;
typedef uint32_t u32;
typedef __attribute__((ext_vector_type(8))) short short8;
typedef __attribute__((ext_vector_type(4))) float f32x4;
typedef __attribute__((ext_vector_type(4))) u32 u32x4;
typedef __attribute__((ext_vector_type(4))) unsigned short u16x4;

#define BS_ 4096   // B*S rows
#define S_ 2048
#define HID_ 2048
#define KVB 32

__device__ __forceinline__ float bf2f(u16 u) { union { u32 i; float f; } v; v.i = ((u32)u) << 16; return v.f; }
__device__ __forceinline__ u16 f2bf(float f) {
  union { float f; u32 i; } v; v.f = f;
  u32 r = v.i + 0x7fffu + ((v.i >> 16) & 1u);
  return (u16)(r >> 16);
}

__device__ __forceinline__ void gload16(const void* gsrc, void* ldst) {
  __builtin_amdgcn_global_load_lds(
      (const __attribute__((address_space(1))) void*)gsrc,
      (__attribute__((address_space(3))) void*)ldst, 16, 0, 0);
}

// ---------------- elementwise convert fp32 -> bf16 ----------------
__global__ __launch_bounds__(256) void conv_f2b(const float* __restrict__ in, u16* __restrict__ out, int n4) {
  int i = blockIdx.x * 256 + threadIdx.x;
  if (i < n4) {
    float4 v = ((const float4*)in)[i];
    u16x4 o;
    o.x = f2bf(v.x); o.y = f2bf(v.y); o.z = f2bf(v.z); o.w = f2bf(v.w);
    ((u16x4*)out)[i] = o;
  }
}

// ---------------- transpose + convert: W[K][N] fp32 -> WT[N][K] bf16 ----------------
__global__ __launch_bounds__(256) void transpose_conv(const float* __restrict__ W, u16* __restrict__ WT,
                                                      int K, int N) {
  __shared__ float tile[64][65];
  const int t = threadIdx.x;
  const int kb = blockIdx.y * 64, nb = blockIdx.x * 64;
#pragma unroll
  for (int c = 0; c < 4; ++c) {
    int idx = c * 256 + t;          // 0..1023, 4 floats each
    int row = idx >> 4;             // 64 rows
    int col4 = (idx & 15) * 4;
    float4 v = *(const float4*)&W[(size_t)(kb + row) * N + nb + col4];
    tile[row][col4 + 0] = v.x; tile[row][col4 + 1] = v.y;
    tile[row][col4 + 2] = v.z; tile[row][col4 + 3] = v.w;
  }
  __syncthreads();
#pragma unroll
  for (int c = 0; c < 4; ++c) {
    int idx = c * 256 + t;
    int n = idx >> 4;
    int k4 = (idx & 15) * 4;
    u16x4 o;
    o.x = f2bf(tile[k4 + 0][n]); o.y = f2bf(tile[k4 + 1][n]);
    o.z = f2bf(tile[k4 + 2][n]); o.w = f2bf(tile[k4 + 3][n]);
    *(u16x4*)&WT[(size_t)(nb + n) * K + kb + k4] = o;
  }
}

// ---------------- RoPE table: [2048][64] cos/sin ----------------
__global__ __launch_bounds__(256) void rope_table(float* __restrict__ ct, float* __restrict__ st) {
  int idx = blockIdx.x * 256 + threadIdx.x;   // 2048*64
  int pos = idx >> 6, i = idx & 63;
  float inv = powf(10000.f, -(float)i / 64.f);
  float a = (float)pos * inv;
  ct[idx] = cosf(a);
  st[idx] = sinf(a);
}

// ---------------- RoPE apply in-place on bf16 [4096][2048] (u32 = pair) ----------------
__global__ __launch_bounds__(256) void rope_apply(u32* __restrict__ buf, const float* __restrict__ ct,
                                                  const float* __restrict__ st) {
  int idx = blockIdx.x * 256 + threadIdx.x;   // 4096*1024 pairs
  int s = (idx >> 10) & 2047;
  int i = idx & 63;
  u32 v = buf[idx];
  float x1 = bf2f((u16)(v & 0xffff)), x2 = bf2f((u16)(v >> 16));
  float c = ct[s * 64 + i], sn = st[s * 64 + i];
  float o1 = x1 * c - x2 * sn;
  float o2 = x1 * sn + x2 * c;
  buf[idx] = (u32)f2bf(o1) | ((u32)f2bf(o2) << 16);
}

// ---------------- GEMM: C[M][N] = A[M][K](bf16) * BT[N][K]^T(bf16) + bias ----------------
template <int OUTF32>
__global__ __launch_bounds__(256) void gemm_bt(const u16* __restrict__ A, const u16* __restrict__ BT,
                                               const float* __restrict__ bias, void* __restrict__ Cout,
                                               int M, int N, int K) {
  __shared__ u16 As[128 * 64];
  __shared__ u16 Bs[128 * 64];
  const int t = threadIdx.x;
  const int lane = t & 63, wave = t >> 6;
  const int wm = wave >> 1, wn = wave & 1;
  const int tm = blockIdx.y, tn = blockIdx.x;
  const int r16 = lane & 15, q4 = lane >> 4;

  f32x4 acc[4][4];
#pragma unroll
  for (int m = 0; m < 4; ++m)
#pragma unroll
    for (int n = 0; n < 4; ++n) acc[m][n] = (f32x4){0.f, 0.f, 0.f, 0.f};

  for (int kt = 0; kt < K; kt += 64) {
#pragma unroll
    for (int c = 0; c < 4; ++c) {
      int idx = c * 256 + t;
      int row = idx >> 3, ch = idx & 7;
      gload16(&A[(size_t)(tm * 128 + row) * K + kt + ch * 8], (char*)As + idx * 16);
      gload16(&BT[(size_t)(tn * 128 + row) * K + kt + ch * 8], (char*)Bs + idx * 16);
    }
    __syncthreads();
#pragma unroll
    for (int kk = 0; kk < 64; kk += 32) {
      short8 af[4], bfv[4];
#pragma unroll
      for (int m = 0; m < 4; ++m)
        af[m] = *(const short8*)&As[(wm * 64 + m * 16 + r16) * 64 + kk + q4 * 8];
#pragma unroll
      for (int n = 0; n < 4; ++n)
        bfv[n] = *(const short8*)&Bs[(wn * 64 + n * 16 + r16) * 64 + kk + q4 * 8];
#pragma unroll
      for (int m = 0; m < 4; ++m)
#pragma unroll
        for (int n = 0; n < 4; ++n)
          acc[m][n] = __builtin_amdgcn_mfma_f32_16x16x32_bf16(af[m], bfv[n], acc[m][n], 0, 0, 0);
    }
    __syncthreads();
  }
#pragma unroll
  for (int n = 0; n < 4; ++n) {
    int gc = tn * 128 + wn * 64 + n * 16 + r16;
    float bv = bias[gc];
#pragma unroll
    for (int m = 0; m < 4; ++m) {
      int gr0 = tm * 128 + wm * 64 + m * 16 + q4 * 4;
#pragma unroll
      for (int j = 0; j < 4; ++j) {
        float v = acc[m][n][j] + bv;
        if (OUTF32)
          ((float*)Cout)[(size_t)(gr0 + j) * N + gc] = v;
        else
          ((u16*)Cout)[(size_t)(gr0 + j) * N + gc] = f2bf(v);
      }
    }
  }
}

// ---------------- causal flash attention v2 ----------------
// 1024 blocks: b -> xcd=b&7, qt_rev=(b>>3)&31, g=b>>8; bh=xcd+8g; qt=31-qt_rev.
// Block: 64 q-rows (qt*64..+63), 4 waves x 16 rows. KV tiles of 32, K double-buffered
// (global_load_lds, pre-swizzled source), V single-buffered reg-staged deferred write.
__global__ __launch_bounds__(256, 4) void attn_kernel(const u16* __restrict__ Q, const u16* __restrict__ K,
                                                      const u16* __restrict__ V, u16* __restrict__ O) {
  __shared__ u16 Kl[2][KVB * 128];   // 8KB each, XOR-swizzled rows
  __shared__ u16 Vt[128 * KVB];      // [d][kv], 8KB, XOR-swizzled
  __shared__ u16 Pl[4][16 * KVB];    // per-wave P, 1KB each
  const int t = threadIdx.x;
  const int lane = t & 63, w = t >> 6;
  const int r16 = lane & 15, q4 = lane >> 4;
  const int b = blockIdx.x;
  const int xcd = b & 7, qt_rev = (b >> 3) & 31, g = b >> 8;
  const int bh = xcd + 8 * g;
  const int qt = 31 - qt_rev;
  const int bb = bh >> 4, h = bh & 15;
  const size_t headoff = (size_t)bb * S_ * HID_ + (size_t)h * 128;
  const u16* Qb = Q + headoff;
  const u16* Kb = K + headoff;
  const u16* Vb = V + headoff;
  u16* Ob = O + headoff;
  const int qrow0 = qt * 64 + w * 16;

  short8 qf[4];
#pragma unroll
  for (int dk = 0; dk < 4; ++dk)
    qf[dk] = *(const short8*)&Qb[(size_t)(qrow0 + r16) * HID_ + dk * 32 + q4 * 8];

  f32x4 ao[8];
  float mr[4], lr[4];
#pragma unroll
  for (int dn = 0; dn < 8; ++dn) ao[dn] = (f32x4){0.f, 0.f, 0.f, 0.f};
#pragma unroll
  for (int j = 0; j < 4; ++j) { mr[j] = -1e30f; lr[j] = 0.f; }

  const int nt = 2 * qt + 2;
  const int kvp = t & 15;          // V staging: kv pair index
  const int vd0 = (t >> 4) * 8;    // V staging: d block

  short8 vr0, vr1;   // V regs in flight

  // prologue: tile 0
#pragma unroll
  for (int c = 0; c < 2; ++c) {
    int idx = c * 256 + t;
    int row = idx >> 4;
    int chs = (idx & 15) ^ (row & 7);
    gload16(&Kb[(size_t)row * HID_ + chs * 8], (char*)Kl[0] + idx * 16);
  }
  vr0 = *(const short8*)&Vb[(size_t)(2 * kvp) * HID_ + vd0];
  vr1 = *(const short8*)&Vb[(size_t)(2 * kvp + 1) * HID_ + vd0];
#pragma unroll
  for (int j = 0; j < 8; ++j) {
    int d = vd0 + j;
    u32 pk = (u32)(u16)vr0[j] | ((u32)(u16)vr1[j] << 16);
    int ba = (d * 64 + kvp * 4) ^ ((d & 3) << 4);
    *(u32*)((char*)Vt + ba) = pk;
  }
  __syncthreads();

  for (int tile = 0; tile < nt; ++tile) {
    const int buf = tile & 1;
    const int kv0 = tile * KVB;
    const bool hasNext = (tile + 1) < nt;
    if (hasNext) {
      const int kvn = (tile + 1) * KVB;
#pragma unroll
      for (int c = 0; c < 2; ++c) {
        int idx = c * 256 + t;
        int row = idx >> 4;
        int chs = (idx & 15) ^ (row & 7);
        gload16(&Kb[(size_t)(kvn + row) * HID_ + chs * 8], (char*)Kl[buf ^ 1] + idx * 16);
      }
      vr0 = *(const short8*)&Vb[(size_t)(kvn + 2 * kvp) * HID_ + vd0];
      vr1 = *(const short8*)&Vb[(size_t)(kvn + 2 * kvp + 1) * HID_ + vd0];
    }

    if (kv0 <= qrow0 + 15) {
      // ---- QK^T ----
      f32x4 sc[2];
      sc[0] = (f32x4){0.f, 0.f, 0.f, 0.f};
      sc[1] = (f32x4){0.f, 0.f, 0.f, 0.f};
#pragma unroll
      for (int dk = 0; dk < 4; ++dk) {
        int ba0 = (r16 * 256 + dk * 64 + q4 * 16) ^ ((r16 & 7) << 4);
        int kr1 = 16 + r16;
        int ba1 = (kr1 * 256 + dk * 64 + q4 * 16) ^ ((kr1 & 7) << 4);
        short8 kf0 = *(const short8*)((const char*)Kl[buf] + ba0);
        short8 kf1 = *(const short8*)((const char*)Kl[buf] + ba1);
        sc[0] = __builtin_amdgcn_mfma_f32_16x16x32_bf16(qf[dk], kf0, sc[0], 0, 0, 0);
        sc[1] = __builtin_amdgcn_mfma_f32_16x16x32_bf16(qf[dk], kf1, sc[1], 0, 0, 0);
      }
      // ---- scale + causal mask ----
      const float SCALE = 0.08838834764831845f;
      const bool need_mask = (kv0 + 31 > qrow0);
#pragma unroll
      for (int n = 0; n < 2; ++n)
#pragma unroll
        for (int j = 0; j < 4; ++j) {
          float sv = sc[n][j] * SCALE;
          if (need_mask) {
            int row = qrow0 + q4 * 4 + j;
            int col = kv0 + n * 16 + r16;
            if (col > row) sv = -1e30f;
          }
          sc[n][j] = sv;
        }
      // ---- softmax (rows in 16-lane groups), defer-max ----
      float tmax[4];
#pragma unroll
      for (int j = 0; j < 4; ++j) {
        float tm = fmaxf(sc[0][j], sc[1][j]);
        tm = fmaxf(tm, __shfl_xor(tm, 1));
        tm = fmaxf(tm, __shfl_xor(tm, 2));
        tm = fmaxf(tm, __shfl_xor(tm, 4));
        tm = fmaxf(tm, __shfl_xor(tm, 8));
        tmax[j] = tm;
      }
      float growth = fmaxf(fmaxf(tmax[0] - mr[0], tmax[1] - mr[1]),
                           fmaxf(tmax[2] - mr[2], tmax[3] - mr[3]));
      if (!__all(growth <= 8.0f)) {
#pragma unroll
        for (int j = 0; j < 4; ++j) {
          float mnew = fmaxf(mr[j], tmax[j]);
          float fsc = __expf(mr[j] - mnew);
          lr[j] *= fsc;
          mr[j] = mnew;
#pragma unroll
          for (int dn = 0; dn < 8; ++dn) ao[dn][j] *= fsc;
        }
      }
#pragma unroll
      for (int j = 0; j < 4; ++j) {
        float p0 = __expf(sc[0][j] - mr[j]);
        float p1 = __expf(sc[1][j] - mr[j]);
        sc[0][j] = p0; sc[1][j] = p1;
        float ps = p0 + p1;
        ps += __shfl_xor(ps, 1);
        ps += __shfl_xor(ps, 2);
        ps += __shfl_xor(ps, 4);
        ps += __shfl_xor(ps, 8);
        lr[j] += ps;
      }
      // ---- P -> LDS (per-wave, swizzled) ----
      u16* Pw = &Pl[w][0];
#pragma unroll
      for (int n = 0; n < 2; ++n)
#pragma unroll
        for (int j = 0; j < 4; ++j) {
          int row = q4 * 4 + j;
          int col = n * 16 + r16;
          int ba = (row * 64 + col * 2) ^ ((row & 3) << 4);
          *(u16*)((char*)Pw + ba) = f2bf(sc[n][j]);
        }
      // ---- PV ----
      {
        int bap = (r16 * 64 + q4 * 16) ^ ((r16 & 3) << 4);
        short8 pa = *(const short8*)((const char*)Pw + bap);
#pragma unroll
        for (int dn = 0; dn < 8; ++dn) {
          int dr = dn * 16 + r16;
          int bav = (dr * 64 + q4 * 16) ^ ((dr & 3) << 4);
          short8 vf = *(const short8*)((const char*)Vt + bav);
          ao[dn] = __builtin_amdgcn_mfma_f32_16x16x32_bf16(pa, vf, ao[dn], 0, 0, 0);
        }
      }
    }
    __syncthreads();   // drains vmcnt: K(t+1) landed for everyone; Vt readers done
    if (hasNext) {
#pragma unroll
      for (int j = 0; j < 8; ++j) {
        int d = vd0 + j;
        u32 pk = (u32)(u16)vr0[j] | ((u32)(u16)vr1[j] << 16);
        int ba = (d * 64 + kvp * 4) ^ ((d & 3) << 4);
        *(u32*)((char*)Vt + ba) = pk;
      }
    }
    __syncthreads();   // V(t+1) visible
  }
  // ---- epilogue ----
#pragma unroll
  for (int j = 0; j < 4; ++j) {
    float inv = 1.f / lr[j];
    int row = qrow0 + q4 * 4 + j;
#pragma unroll
    for (int dn = 0; dn < 8; ++dn)
      Ob[(size_t)row * HID_ + dn * 16 + r16] = f2bf(ao[dn][j] * inv);
  }
}

// ---------------- host launch ----------------
extern "C" void kernel_launch(void* const* d_in, const int* in_sizes, int n_in,
                              void* d_out, int out_size, void* d_ws, size_t ws_size,
                              hipStream_t stream) {
  (void)in_sizes; (void)n_in; (void)out_size; (void)ws_size;
  const float* x     = (const float*)d_in[0];
  const float* W_dkv = (const float*)d_in[2];
  const float* b_dkv = (const float*)d_in[3];
  const float* W_uk  = (const float*)d_in[4];
  const float* b_uk  = (const float*)d_in[5];
  const float* W_uv  = (const float*)d_in[6];
  const float* b_uv  = (const float*)d_in[7];
  const float* W_dq  = (const float*)d_in[8];
  const float* b_dq  = (const float*)d_in[9];
  const float* W_uq  = (const float*)d_in[10];
  const float* b_uq  = (const float*)d_in[11];
  const float* W_o   = (const float*)d_in[12];
  const float* b_o   = (const float*)d_in[13];
  float* out = (float*)d_out;

  char* ws = (char*)d_ws;
  size_t off = 0;
  auto carve = [&](size_t bytes) { void* p = ws + off; off += (bytes + 255) & ~(size_t)255; return p; };
  u16* xb    = (u16*)carve((size_t)BS_ * 2048 * 2);
  u16* WdkvT = (u16*)carve((size_t)512 * 2048 * 2);
  u16* WukT  = (u16*)carve((size_t)2048 * 512 * 2);
  u16* WuvT  = (u16*)carve((size_t)2048 * 512 * 2);
  u16* WdqT  = (u16*)carve((size_t)1536 * 2048 * 2);
  u16* WuqT  = (u16*)carve((size_t)2048 * 1536 * 2);
  u16* WoT   = (u16*)carve((size_t)2048 * 2048 * 2);
  u16* kvb   = (u16*)carve((size_t)BS_ * 512 * 2);
  u16* q1b   = (u16*)carve((size_t)BS_ * 1536 * 2);
  u16* qb    = (u16*)carve((size_t)BS_ * 2048 * 2);
  u16* kb    = (u16*)carve((size_t)BS_ * 2048 * 2);
  u16* vb    = (u16*)carve((size_t)BS_ * 2048 * 2);
  u16* aob   = (u16*)carve((size_t)BS_ * 2048 * 2);
  float* ct  = (float*)carve((size_t)2048 * 64 * 4);
  float* st  = (float*)carve((size_t)2048 * 64 * 4);

  conv_f2b<<<dim3(BS_ * 2048 / 4 / 256), 256, 0, stream>>>(x, xb, BS_ * 2048 / 4);
  transpose_conv<<<dim3(512 / 64, 2048 / 64), 256, 0, stream>>>(W_dkv, WdkvT, 2048, 512);
  transpose_conv<<<dim3(2048 / 64, 512 / 64), 256, 0, stream>>>(W_uk, WukT, 512, 2048);
  transpose_conv<<<dim3(2048 / 64, 512 / 64), 256, 0, stream>>>(W_uv, WuvT, 512, 2048);
  transpose_conv<<<dim3(1536 / 64, 2048 / 64), 256, 0, stream>>>(W_dq, WdqT, 2048, 1536);
  transpose_conv<<<dim3(2048 / 64, 1536 / 64), 256, 0, stream>>>(W_uq, WuqT, 1536, 2048);
  transpose_conv<<<dim3(2048 / 64, 2048 / 64), 256, 0, stream>>>(W_o, WoT, 2048, 2048);
  rope_table<<<dim3(512), 256, 0, stream>>>(ct, st);

  gemm_bt<0><<<dim3(512 / 128, BS_ / 128), 256, 0, stream>>>(xb, WdkvT, b_dkv, kvb, BS_, 512, 2048);
  gemm_bt<0><<<dim3(1536 / 128, BS_ / 128), 256, 0, stream>>>(xb, WdqT, b_dq, q1b, BS_, 1536, 2048);
  gemm_bt<0><<<dim3(2048 / 128, BS_ / 128), 256, 0, stream>>>(kvb, WukT, b_uk, kb, BS_, 2048, 512);
  gemm_bt<0><<<dim3(2048 / 128, BS_ / 128), 256, 0, stream>>>(kvb, WuvT, b_uv, vb, BS_, 2048, 512);
  gemm_bt<0><<<dim3(2048 / 128, BS_ / 128), 256, 0, stream>>>(q1b, WuqT, b_uq, qb, BS_, 2048, 1536);

  rope_apply<<<dim3(BS_ * 1024 / 256), 256, 0, stream>>>((u32*)qb, ct, st);
  rope_apply<<<dim3(BS_ * 1024 / 256), 256, 0, stream>>>((u32*)kb, ct, st);

  attn_kernel<<<dim3(1024), 256, 0, stream>>>(qb, kb, vb, aob);

  gemm_bt<1><<<dim3(2048 / 128, BS_ / 128), 256, 0, stream>>>(aob, WoT, b_o, out, BS_, 2048, 2048);
}

// Round 4
// 415.773 us; speedup vs baseline: 1.5435x; 1.1286x over previous
//
#include <hip/hip_runtime.h>
#include <stdint.h>

typedef unsigned short u16;
typedef uint32_t u32;
typedef __attribute__((ext_vector_type(8))) short short8;
typedef __attribute__((ext_vector_type(4))) float f32x4;
typedef __attribute__((ext_vector_type(4))) u32 u32x4;
typedef __attribute__((ext_vector_type(4))) unsigned short u16x4;

#define BS_ 4096   // B*S rows
#define S_ 2048
#define HID_ 2048
#define KVB 64

__device__ __forceinline__ float bf2f(u16 u) { union { u32 i; float f; } v; v.i = ((u32)u) << 16; return v.f; }
__device__ __forceinline__ u16 f2bf(float f) {
  union { float f; u32 i; } v; v.f = f;
  u32 r = v.i + 0x7fffu + ((v.i >> 16) & 1u);
  return (u16)(r >> 16);
}

__device__ __forceinline__ void gload16(const void* gsrc, void* ldst) {
  __builtin_amdgcn_global_load_lds(
      (const __attribute__((address_space(1))) void*)gsrc,
      (__attribute__((address_space(3))) void*)ldst, 16, 0, 0);
}

// ---------------- elementwise convert fp32 -> bf16 ----------------
__global__ __launch_bounds__(256) void conv_f2b(const float* __restrict__ in, u16* __restrict__ out, int n4) {
  int i = blockIdx.x * 256 + threadIdx.x;
  if (i < n4) {
    float4 v = ((const float4*)in)[i];
    u16x4 o;
    o.x = f2bf(v.x); o.y = f2bf(v.y); o.z = f2bf(v.z); o.w = f2bf(v.w);
    ((u16x4*)out)[i] = o;
  }
}

// ---------------- transpose + convert: W[K][N] fp32 -> WT[N][K] bf16 ----------------
__global__ __launch_bounds__(256) void transpose_conv(const float* __restrict__ W, u16* __restrict__ WT,
                                                      int K, int N) {
  __shared__ float tile[64][65];
  const int t = threadIdx.x;
  const int kb = blockIdx.y * 64, nb = blockIdx.x * 64;
#pragma unroll
  for (int c = 0; c < 4; ++c) {
    int idx = c * 256 + t;
    int row = idx >> 4;
    int col4 = (idx & 15) * 4;
    float4 v = *(const float4*)&W[(size_t)(kb + row) * N + nb + col4];
    tile[row][col4 + 0] = v.x; tile[row][col4 + 1] = v.y;
    tile[row][col4 + 2] = v.z; tile[row][col4 + 3] = v.w;
  }
  __syncthreads();
#pragma unroll
  for (int c = 0; c < 4; ++c) {
    int idx = c * 256 + t;
    int n = idx >> 4;
    int k4 = (idx & 15) * 4;
    u16x4 o;
    o.x = f2bf(tile[k4 + 0][n]); o.y = f2bf(tile[k4 + 1][n]);
    o.z = f2bf(tile[k4 + 2][n]); o.w = f2bf(tile[k4 + 3][n]);
    *(u16x4*)&WT[(size_t)(nb + n) * K + kb + k4] = o;
  }
}

// ---------------- V transpose: vb[b][s][h*128+d] -> VT[(b*16+h)][d][s] ----------------
__global__ __launch_bounds__(256) void vtrans(const u16* __restrict__ Vin, u16* __restrict__ VT) {
  __shared__ u16 tile[64][136];   // pad 136 elems: 16B-aligned rows, bank-rotating stride
  const int t = threadIdx.x;
  const int st0 = blockIdx.x * 64;
  const int bh = blockIdx.y;
  const int bb = bh >> 4, h = bh & 15;
  const u16* src = Vin + (size_t)bb * S_ * HID_ + (size_t)h * 128;
  u16* dst = VT + (size_t)bh * 128 * S_;
#pragma unroll
  for (int c = 0; c < 4; ++c) {
    int idx = c * 256 + t;          // 1024 chunks: 64 s-rows x 16 chunks
    int s = idx >> 4, ch = idx & 15;
    short8 v = *(const short8*)&src[(size_t)(st0 + s) * HID_ + ch * 8];
    *(short8*)&tile[s][ch * 8] = v;
  }
  __syncthreads();
#pragma unroll
  for (int c = 0; c < 4; ++c) {
    int idx = c * 256 + t;          // 1024 chunks: 128 d-rows x 8 chunks
    int d = idx >> 3, ch = idx & 7;
    short8 o;
#pragma unroll
    for (int j = 0; j < 8; ++j) o[j] = tile[ch * 8 + j][d];
    *(short8*)&dst[(size_t)d * S_ + st0 + ch * 8] = o;
  }
}

// ---------------- RoPE table ----------------
__global__ __launch_bounds__(256) void rope_table(float* __restrict__ ct, float* __restrict__ st) {
  int idx = blockIdx.x * 256 + threadIdx.x;
  int pos = idx >> 6, i = idx & 63;
  float inv = powf(10000.f, -(float)i / 64.f);
  float a = (float)pos * inv;
  ct[idx] = cosf(a);
  st[idx] = sinf(a);
}

// ---------------- RoPE apply ----------------
__global__ __launch_bounds__(256) void rope_apply(u32* __restrict__ buf, const float* __restrict__ ct,
                                                  const float* __restrict__ st) {
  int idx = blockIdx.x * 256 + threadIdx.x;
  int s = (idx >> 10) & 2047;
  int i = idx & 63;
  u32 v = buf[idx];
  float x1 = bf2f((u16)(v & 0xffff)), x2 = bf2f((u16)(v >> 16));
  float c = ct[s * 64 + i], sn = st[s * 64 + i];
  float o1 = x1 * c - x2 * sn;
  float o2 = x1 * sn + x2 * c;
  buf[idx] = (u32)f2bf(o1) | ((u32)f2bf(o2) << 16);
}

// ---------------- GEMM (m97-structure) ----------------
template <int OUTF32>
__global__ __launch_bounds__(256) void gemm_bt(const u16* __restrict__ A, const u16* __restrict__ BT,
                                               const float* __restrict__ bias, void* __restrict__ Cout,
                                               int M, int N, int K) {
  __shared__ u16 As[128 * 64];
  __shared__ u16 Bs[128 * 64];
  const int t = threadIdx.x;
  const int lane = t & 63, wave = t >> 6;
  const int wm = wave >> 1, wn = wave & 1;
  const int tm = blockIdx.y, tn = blockIdx.x;
  const int r16 = lane & 15, q4 = lane >> 4;

  f32x4 acc[4][4];
#pragma unroll
  for (int m = 0; m < 4; ++m)
#pragma unroll
    for (int n = 0; n < 4; ++n) acc[m][n] = (f32x4){0.f, 0.f, 0.f, 0.f};

  for (int kt = 0; kt < K; kt += 64) {
#pragma unroll
    for (int c = 0; c < 4; ++c) {
      int idx = c * 256 + t;
      int row = idx >> 3, ch = idx & 7;
      gload16(&A[(size_t)(tm * 128 + row) * K + kt + ch * 8], (char*)As + idx * 16);
      gload16(&BT[(size_t)(tn * 128 + row) * K + kt + ch * 8], (char*)Bs + idx * 16);
    }
    __syncthreads();
#pragma unroll
    for (int kk = 0; kk < 64; kk += 32) {
      short8 af[4], bfv[4];
#pragma unroll
      for (int m = 0; m < 4; ++m)
        af[m] = *(const short8*)&As[(wm * 64 + m * 16 + r16) * 64 + kk + q4 * 8];
#pragma unroll
      for (int n = 0; n < 4; ++n)
        bfv[n] = *(const short8*)&Bs[(wn * 64 + n * 16 + r16) * 64 + kk + q4 * 8];
#pragma unroll
      for (int m = 0; m < 4; ++m)
#pragma unroll
        for (int n = 0; n < 4; ++n)
          acc[m][n] = __builtin_amdgcn_mfma_f32_16x16x32_bf16(af[m], bfv[n], acc[m][n], 0, 0, 0);
    }
    __syncthreads();
  }
#pragma unroll
  for (int n = 0; n < 4; ++n) {
    int gc = tn * 128 + wn * 64 + n * 16 + r16;
    float bv = bias[gc];
#pragma unroll
    for (int m = 0; m < 4; ++m) {
      int gr0 = tm * 128 + wm * 64 + m * 16 + q4 * 4;
#pragma unroll
      for (int j = 0; j < 4; ++j) {
        float v = acc[m][n][j] + bv;
        if (OUTF32)
          ((float*)Cout)[(size_t)(gr0 + j) * N + gc] = v;
        else
          ((u16*)Cout)[(size_t)(gr0 + j) * N + gc] = f2bf(v);
      }
    }
  }
}

// ---------------- causal flash attention v4 ----------------
// 512 blocks. b -> xcd=b&7, l=b>>3: r=l>>5, i=l&31; bh=xcd+8*((i>>4)+2r);
// qt = r ? (i&15) : 15-(i&15).  Blocks c and c+256 share (xcd,i) -> qt pair sums to 15
// (constant 34 tiles per CU under breadth-first dispatch).
// Block: 128 q-rows, 4 waves x 32 rows (M=2). KVB=64; K tile [64][128] and
// V^T tile [128][64] double-buffered via global_load_lds w/ chunk-XOR swizzle.
__global__ __launch_bounds__(256, 2) void attn_kernel(const u16* __restrict__ Q, const u16* __restrict__ K,
                                                      const u16* __restrict__ VT, u16* __restrict__ O) {
  __shared__ u16 Kl[2][KVB * 128];   // 16KB each
  __shared__ u16 Vl[2][128 * KVB];   // 16KB each (rows = d, 128B/row)
  __shared__ u16 Pl[4][32 * 64];     // per-wave P, 4KB each
  const int t = threadIdx.x;
  const int lane = t & 63, w = t >> 6;
  const int r16 = lane & 15, q4 = lane >> 4;
  const int b = blockIdx.x;
  const int xcd = b & 7;
  const int l = b >> 3;
  const int r = l >> 5, i = l & 31;
  const int bh = xcd + 8 * ((i >> 4) + 2 * r);
  const int qt = r ? (i & 15) : 15 - (i & 15);
  const int bb = bh >> 4, h = bh & 15;
  const size_t headoff = (size_t)bb * S_ * HID_ + (size_t)h * 128;
  const u16* Qb = Q + headoff;
  const u16* Kb = K + headoff;
  const u16* VTb = VT + (size_t)bh * 128 * S_;
  u16* Ob = O + headoff;
  const int qrow0 = qt * 128 + w * 32;

  short8 qf[2][4];
#pragma unroll
  for (int m = 0; m < 2; ++m)
#pragma unroll
    for (int dk = 0; dk < 4; ++dk)
      qf[m][dk] = *(const short8*)&Qb[(size_t)(qrow0 + m * 16 + r16) * HID_ + dk * 32 + q4 * 8];

  f32x4 ao[2][8];
  float mr[2][4], lr[2][4];
#pragma unroll
  for (int m = 0; m < 2; ++m) {
#pragma unroll
    for (int dn = 0; dn < 8; ++dn) ao[m][dn] = (f32x4){0.f, 0.f, 0.f, 0.f};
#pragma unroll
    for (int j = 0; j < 4; ++j) { mr[m][j] = -1e30f; lr[m][j] = 0.f; }
  }

  const int nt = 2 * qt + 2;

  auto stage = [&](int buf, int kvbase) {
    // K tile: 64 rows x 256B (16 chunks), chunk-XOR on source, linear LDS dest
#pragma unroll
    for (int c = 0; c < 4; ++c) {
      int s = c * 256 + t;
      int row = s >> 4;
      int chs = (s & 15) ^ (row & 7);
      gload16(&Kb[(size_t)(kvbase + row) * HID_ + chs * 8], (char*)Kl[buf] + s * 16);
    }
    // V^T tile: 128 rows x 128B (8 chunks), chunk-XOR on source, linear LDS dest
#pragma unroll
    for (int c = 0; c < 4; ++c) {
      int s = c * 256 + t;
      int row = s >> 3;
      int chs = (s & 7) ^ (row & 7);
      gload16(&VTb[(size_t)row * S_ + kvbase + chs * 8], (char*)Vl[buf] + s * 16);
    }
  };

  stage(0, 0);
  __syncthreads();

  for (int tile = 0; tile < nt; ++tile) {
    const int buf = tile & 1;
    const int kv0 = tile * KVB;
    if (tile + 1 < nt) stage(buf ^ 1, kv0 + KVB);

    if (kv0 <= qrow0 + 31) {
      // ---- QK^T ----
      f32x4 sc[2][4];
#pragma unroll
      for (int m = 0; m < 2; ++m)
#pragma unroll
        for (int n = 0; n < 4; ++n) sc[m][n] = (f32x4){0.f, 0.f, 0.f, 0.f};
#pragma unroll
      for (int dk = 0; dk < 4; ++dk) {
        short8 kf[4];
#pragma unroll
        for (int n = 0; n < 4; ++n) {
          int kr = n * 16 + r16;
          int ba = (kr * 256 + dk * 64 + q4 * 16) ^ ((kr & 7) << 4);
          kf[n] = *(const short8*)((const char*)Kl[buf] + ba);
        }
#pragma unroll
        for (int m = 0; m < 2; ++m)
#pragma unroll
          for (int n = 0; n < 4; ++n)
            sc[m][n] = __builtin_amdgcn_mfma_f32_16x16x32_bf16(qf[m][dk], kf[n], sc[m][n], 0, 0, 0);
      }
      // ---- scale + causal mask ----
      const float SCALE = 0.08838834764831845f;
      const bool need_mask = (kv0 + 63 > qrow0);
#pragma unroll
      for (int m = 0; m < 2; ++m)
#pragma unroll
        for (int n = 0; n < 4; ++n)
#pragma unroll
          for (int j = 0; j < 4; ++j) {
            float sv = sc[m][n][j] * SCALE;
            if (need_mask) {
              int row = qrow0 + m * 16 + q4 * 4 + j;
              int col = kv0 + n * 16 + r16;
              if (col > row) sv = -1e30f;
            }
            sc[m][n][j] = sv;
          }
      // ---- online softmax with defer-max ----
      float tmax[2][4];
#pragma unroll
      for (int m = 0; m < 2; ++m)
#pragma unroll
        for (int j = 0; j < 4; ++j) {
          float tm = fmaxf(fmaxf(sc[m][0][j], sc[m][1][j]), fmaxf(sc[m][2][j], sc[m][3][j]));
          tm = fmaxf(tm, __shfl_xor(tm, 1));
          tm = fmaxf(tm, __shfl_xor(tm, 2));
          tm = fmaxf(tm, __shfl_xor(tm, 4));
          tm = fmaxf(tm, __shfl_xor(tm, 8));
          tmax[m][j] = tm;
        }
      float growth = -1e30f;
#pragma unroll
      for (int m = 0; m < 2; ++m)
#pragma unroll
        for (int j = 0; j < 4; ++j) growth = fmaxf(growth, tmax[m][j] - mr[m][j]);
      if (!__all(growth <= 8.0f)) {
#pragma unroll
        for (int m = 0; m < 2; ++m)
#pragma unroll
          for (int j = 0; j < 4; ++j) {
            float mnew = fmaxf(mr[m][j], tmax[m][j]);
            float fsc = __expf(mr[m][j] - mnew);
            lr[m][j] *= fsc;
            mr[m][j] = mnew;
#pragma unroll
            for (int dn = 0; dn < 8; ++dn) ao[m][dn][j] *= fsc;
          }
      }
#pragma unroll
      for (int m = 0; m < 2; ++m)
#pragma unroll
        for (int j = 0; j < 4; ++j) {
          float ps = 0.f;
#pragma unroll
          for (int n = 0; n < 4; ++n) {
            float p = __expf(sc[m][n][j] - mr[m][j]);
            sc[m][n][j] = p;
            ps += p;
          }
          ps += __shfl_xor(ps, 1);
          ps += __shfl_xor(ps, 2);
          ps += __shfl_xor(ps, 4);
          ps += __shfl_xor(ps, 8);
          lr[m][j] += ps;
        }
      // ---- P -> LDS (per-wave, XOR-swizzled) ----
      u16* Pw = &Pl[w][0];
#pragma unroll
      for (int m = 0; m < 2; ++m)
#pragma unroll
        for (int n = 0; n < 4; ++n)
#pragma unroll
          for (int j = 0; j < 4; ++j) {
            int row = m * 16 + q4 * 4 + j;
            int col = n * 16 + r16;
            int ba = (row * 128 + col * 2) ^ ((row & 7) << 4);
            *(u16*)((char*)Pw + ba) = f2bf(sc[m][n][j]);
          }
      // ---- PV:  ao[m][dn] += P[m] x V^T-fragment (plain swizzled ds_read) ----
#pragma unroll
      for (int ck = 0; ck < 2; ++ck) {
        short8 pa[2];
#pragma unroll
        for (int m = 0; m < 2; ++m) {
          int row = m * 16 + r16;
          int ba = (row * 128 + ck * 64 + q4 * 16) ^ ((row & 7) << 4);
          pa[m] = *(const short8*)((const char*)Pw + ba);
        }
#pragma unroll
        for (int dn = 0; dn < 8; ++dn) {
          int dr = dn * 16 + r16;
          int ba = (dr * 128 + ck * 64 + q4 * 16) ^ ((dr & 7) << 4);
          short8 vf = *(const short8*)((const char*)Vl[buf] + ba);
#pragma unroll
          for (int m = 0; m < 2; ++m)
            ao[m][dn] = __builtin_amdgcn_mfma_f32_16x16x32_bf16(pa[m], vf, ao[m][dn], 0, 0, 0);
        }
      }
    }
    __syncthreads();   // drains vmcnt: next tile's K/V DMA complete; buffers safe to swap
  }
  // ---- epilogue ----
#pragma unroll
  for (int m = 0; m < 2; ++m)
#pragma unroll
    for (int j = 0; j < 4; ++j) {
      float inv = 1.f / lr[m][j];
      int row = qrow0 + m * 16 + q4 * 4 + j;
#pragma unroll
      for (int dn = 0; dn < 8; ++dn)
        Ob[(size_t)row * HID_ + dn * 16 + r16] = f2bf(ao[m][dn][j] * inv);
    }
}

// ---------------- host launch ----------------
extern "C" void kernel_launch(void* const* d_in, const int* in_sizes, int n_in,
                              void* d_out, int out_size, void* d_ws, size_t ws_size,
                              hipStream_t stream) {
  (void)in_sizes; (void)n_in; (void)out_size; (void)ws_size;
  const float* x     = (const float*)d_in[0];
  const float* W_dkv = (const float*)d_in[2];
  const float* b_dkv = (const float*)d_in[3];
  const float* W_uk  = (const float*)d_in[4];
  const float* b_uk  = (const float*)d_in[5];
  const float* W_uv  = (const float*)d_in[6];
  const float* b_uv  = (const float*)d_in[7];
  const float* W_dq  = (const float*)d_in[8];
  const float* b_dq  = (const float*)d_in[9];
  const float* W_uq  = (const float*)d_in[10];
  const float* b_uq  = (const float*)d_in[11];
  const float* W_o   = (const float*)d_in[12];
  const float* b_o   = (const float*)d_in[13];
  float* out = (float*)d_out;

  char* ws = (char*)d_ws;
  size_t off = 0;
  auto carve = [&](size_t bytes) { void* p = ws + off; off += (bytes + 255) & ~(size_t)255; return p; };
  u16* xb    = (u16*)carve((size_t)BS_ * 2048 * 2);   // also reused as VT after q1 GEMM
  u16* WdkvT = (u16*)carve((size_t)512 * 2048 * 2);
  u16* WukT  = (u16*)carve((size_t)2048 * 512 * 2);
  u16* WuvT  = (u16*)carve((size_t)2048 * 512 * 2);
  u16* WdqT  = (u16*)carve((size_t)1536 * 2048 * 2);
  u16* WuqT  = (u16*)carve((size_t)2048 * 1536 * 2);
  u16* WoT   = (u16*)carve((size_t)2048 * 2048 * 2);
  u16* kvb   = (u16*)carve((size_t)BS_ * 512 * 2);
  u16* q1b   = (u16*)carve((size_t)BS_ * 1536 * 2);
  u16* qb    = (u16*)carve((size_t)BS_ * 2048 * 2);
  u16* kb    = (u16*)carve((size_t)BS_ * 2048 * 2);
  u16* vb    = (u16*)carve((size_t)BS_ * 2048 * 2);
  u16* aob   = (u16*)carve((size_t)BS_ * 2048 * 2);
  float* ct  = (float*)carve((size_t)2048 * 64 * 4);
  float* st  = (float*)carve((size_t)2048 * 64 * 4);
  u16* VT    = xb;   // xb is dead after the q1 GEMM; reuse for V^T [32][128][2048]

  conv_f2b<<<dim3(BS_ * 2048 / 4 / 256), 256, 0, stream>>>(x, xb, BS_ * 2048 / 4);
  transpose_conv<<<dim3(512 / 64, 2048 / 64), 256, 0, stream>>>(W_dkv, WdkvT, 2048, 512);
  transpose_conv<<<dim3(2048 / 64, 512 / 64), 256, 0, stream>>>(W_uk, WukT, 512, 2048);
  transpose_conv<<<dim3(2048 / 64, 512 / 64), 256, 0, stream>>>(W_uv, WuvT, 512, 2048);
  transpose_conv<<<dim3(1536 / 64, 2048 / 64), 256, 0, stream>>>(W_dq, WdqT, 2048, 1536);
  transpose_conv<<<dim3(2048 / 64, 1536 / 64), 256, 0, stream>>>(W_uq, WuqT, 1536, 2048);
  transpose_conv<<<dim3(2048 / 64, 2048 / 64), 256, 0, stream>>>(W_o, WoT, 2048, 2048);
  rope_table<<<dim3(512), 256, 0, stream>>>(ct, st);

  gemm_bt<0><<<dim3(512 / 128, BS_ / 128), 256, 0, stream>>>(xb, WdkvT, b_dkv, kvb, BS_, 512, 2048);
  gemm_bt<0><<<dim3(1536 / 128, BS_ / 128), 256, 0, stream>>>(xb, WdqT, b_dq, q1b, BS_, 1536, 2048);
  // xb dead from here on
  gemm_bt<0><<<dim3(2048 / 128, BS_ / 128), 256, 0, stream>>>(kvb, WukT, b_uk, kb, BS_, 2048, 512);
  gemm_bt<0><<<dim3(2048 / 128, BS_ / 128), 256, 0, stream>>>(kvb, WuvT, b_uv, vb, BS_, 2048, 512);
  gemm_bt<0><<<dim3(2048 / 128, BS_ / 128), 256, 0, stream>>>(q1b, WuqT, b_uq, qb, BS_, 2048, 1536);

  rope_apply<<<dim3(BS_ * 1024 / 256), 256, 0, stream>>>((u32*)qb, ct, st);
  rope_apply<<<dim3(BS_ * 1024 / 256), 256, 0, stream>>>((u32*)kb, ct, st);
  vtrans<<<dim3(S_ / 64, 32), 256, 0, stream>>>(vb, VT);

  attn_kernel<<<dim3(512), 256, 0, stream>>>(qb, kb, VT, aob);

  gemm_bt<1><<<dim3(2048 / 128, BS_ / 128), 256, 0, stream>>>(aob, WoT, b_o, out, BS_, 2048, 2048);
}